// Round 1
// baseline (592.726 us; speedup 1.0000x reference)
//
#include <hip/hip_runtime.h>

#define N_NODES 50000
#define N_HEDGES 10000
#define DDIM 128

// ---------------- degree histogram ----------------
__global__ __launch_bounds__(256) void hist_deg(
    const int* __restrict__ src, const int* __restrict__ dst, int nnz,
    int* __restrict__ deg_e, int* __restrict__ deg_n) {
  int i = blockIdx.x * 256 + threadIdx.x;
  if (i < nnz) {
    atomicAdd(&deg_e[dst[i]], 1);
    atomicAdd(&deg_n[src[i]], 1);
  }
}

// ---------------- single-block exclusive scan (also seeds cursors) ----------------
__global__ __launch_bounds__(1024) void scan_csr(
    const int* __restrict__ deg, int* __restrict__ offs, int* __restrict__ cur, int n) {
  __shared__ int lsum[1024];
  int t = threadIdx.x;
  int chunk = (n + 1023) >> 10;
  int b = t * chunk;
  int e = min(b + chunk, n);
  int s = 0;
  for (int i = b; i < e; ++i) s += deg[i];
  lsum[t] = s;
  __syncthreads();
  for (int off = 1; off < 1024; off <<= 1) {
    int v = (t >= off) ? lsum[t - off] : 0;
    __syncthreads();
    lsum[t] += v;
    __syncthreads();
  }
  int pref = (t == 0) ? 0 : lsum[t - 1];
  for (int i = b; i < e; ++i) {
    offs[i] = pref;
    cur[i] = pref;
    pref += deg[i];
  }
  if (e == n) offs[n] = pref;  // all tail threads write the same total
}

// ---------------- CSR fill ----------------
__global__ __launch_bounds__(256) void fill_csr(
    const int* __restrict__ src, const int* __restrict__ dst, int nnz,
    int* __restrict__ cur_e, int* __restrict__ cur_n,
    int* __restrict__ adj_e, int* __restrict__ adj_n) {
  int i = blockIdx.x * 256 + threadIdx.x;
  if (i < nnz) {
    int s = src[i], d = dst[i];
    adj_e[atomicAdd(&cur_e[d], 1)] = s;  // per hyperedge: list of src nodes
    adj_n[atomicAdd(&cur_n[s], 1)] = d;  // per node: list of hyperedges
  }
}

// ---------------- GEMM: Y[n_rows,128] = X[n_rows,128] * W[128,128] ----------------
#define ACC4(accv, xv)                                          \
  accv.x += xv.x * w0.x + xv.y * w1.x + xv.z * w2.x + xv.w * w3.x; \
  accv.y += xv.x * w0.y + xv.y * w1.y + xv.z * w2.y + xv.w * w3.y; \
  accv.z += xv.x * w0.z + xv.y * w1.z + xv.z * w2.z + xv.w * w3.z; \
  accv.w += xv.x * w0.w + xv.y * w1.w + xv.z * w2.w + xv.w * w3.w;

__global__ __launch_bounds__(256, 2) void gemm128(
    const float* __restrict__ X, const float* __restrict__ W,
    float* __restrict__ Y, int n_rows) {
  __shared__ float sW[128 * 128];  // 64 KB
  __shared__ float sX[32 * 128];   // 16 KB
  const int t = threadIdx.x;
  {
    const float4* W4 = (const float4*)W;
    float4* sW4w = (float4*)sW;
#pragma unroll
    for (int i = 0; i < 16; ++i) sW4w[t + 256 * i] = W4[t + 256 * i];
  }
  const int lane = t & 63;
  const int wid = t >> 6;
  const int cg = lane & 31;                       // cols [4cg, 4cg+4)
  const int row_in_blk = wid * 8 + (lane >> 5) * 4;  // 4 rows per thread
  const float4* sW4 = (const float4*)sW;

  for (int base = blockIdx.x * 32; base < n_rows; base += gridDim.x * 32) {
    __syncthreads();
    {
      const float4* X4 = (const float4*)(X + (size_t)base * DDIM);
      float4* sX4 = (float4*)sX;
      int limit4 = min(32, n_rows - base) * 32;
#pragma unroll
      for (int i = 0; i < 4; ++i) {
        int idx = t + 256 * i;
        if (idx < limit4) sX4[idx] = X4[idx];
      }
    }
    __syncthreads();
    float4 acc0 = {0, 0, 0, 0}, acc1 = {0, 0, 0, 0}, acc2 = {0, 0, 0, 0}, acc3 = {0, 0, 0, 0};
    const float4* x0 = (const float4*)(sX + (row_in_blk + 0) * DDIM);
    const float4* x1 = (const float4*)(sX + (row_in_blk + 1) * DDIM);
    const float4* x2 = (const float4*)(sX + (row_in_blk + 2) * DDIM);
    const float4* x3 = (const float4*)(sX + (row_in_blk + 3) * DDIM);
#pragma unroll 8
    for (int k4 = 0; k4 < 32; ++k4) {
      float4 w0 = sW4[(4 * k4 + 0) * 32 + cg];
      float4 w1 = sW4[(4 * k4 + 1) * 32 + cg];
      float4 w2 = sW4[(4 * k4 + 2) * 32 + cg];
      float4 w3 = sW4[(4 * k4 + 3) * 32 + cg];
      float4 xa = x0[k4], xb = x1[k4], xc = x2[k4], xd = x3[k4];
      ACC4(acc0, xa)
      ACC4(acc1, xb)
      ACC4(acc2, xc)
      ACC4(acc3, xd)
    }
    int r = base + row_in_blk;
    if (r + 0 < n_rows) ((float4*)(Y + (size_t)(r + 0) * DDIM))[cg] = acc0;
    if (r + 1 < n_rows) ((float4*)(Y + (size_t)(r + 1) * DDIM))[cg] = acc1;
    if (r + 2 < n_rows) ((float4*)(Y + (size_t)(r + 2) * DDIM))[cg] = acc2;
    if (r + 3 < n_rows) ((float4*)(Y + (size_t)(r + 3) * DDIM))[cg] = acc3;
  }
}

// ---------------- segment mean (one wave per segment, 128 cols via float2) ----------------
__global__ __launch_bounds__(256) void seg_mean(
    const float* __restrict__ rows, const int* __restrict__ offs,
    const int* __restrict__ adj, float* __restrict__ out, int n_seg) {
  int w = (int)((blockIdx.x * 256 + threadIdx.x) >> 6);
  int lane = threadIdx.x & 63;
  if (w >= n_seg) return;
  int beg = offs[w], end = offs[w + 1];
  float2 acc = {0.f, 0.f};
  int j = beg;
  for (; j + 2 <= end; j += 2) {
    int s0 = adj[j], s1 = adj[j + 1];
    float2 v0 = ((const float2*)(rows + (size_t)s0 * DDIM))[lane];
    float2 v1 = ((const float2*)(rows + (size_t)s1 * DDIM))[lane];
    acc.x += v0.x + v1.x;
    acc.y += v0.y + v1.y;
  }
  if (j < end) {
    int s0 = adj[j];
    float2 v0 = ((const float2*)(rows + (size_t)s0 * DDIM))[lane];
    acc.x += v0.x;
    acc.y += v0.y;
  }
  float inv = (end > beg) ? 1.0f / (float)(end - beg) : 0.0f;
  float2 r;
  r.x = acc.x * inv;
  r.y = acc.y * inv;
  ((float2*)(out + (size_t)w * DDIM))[lane] = r;
}

template <int RELU>
__global__ __launch_bounds__(256) void seg_mean_bias(
    const float* __restrict__ rows, const int* __restrict__ offs,
    const int* __restrict__ adj, const float* __restrict__ bias,
    float* __restrict__ out, int n_seg) {
  int w = (int)((blockIdx.x * 256 + threadIdx.x) >> 6);
  int lane = threadIdx.x & 63;
  if (w >= n_seg) return;
  int beg = offs[w], end = offs[w + 1];
  float2 acc = {0.f, 0.f};
  int j = beg;
  for (; j + 2 <= end; j += 2) {
    int s0 = adj[j], s1 = adj[j + 1];
    float2 v0 = ((const float2*)(rows + (size_t)s0 * DDIM))[lane];
    float2 v1 = ((const float2*)(rows + (size_t)s1 * DDIM))[lane];
    acc.x += v0.x + v1.x;
    acc.y += v0.y + v1.y;
  }
  if (j < end) {
    int s0 = adj[j];
    float2 v0 = ((const float2*)(rows + (size_t)s0 * DDIM))[lane];
    acc.x += v0.x;
    acc.y += v0.y;
  }
  float inv = (end > beg) ? 1.0f / (float)(end - beg) : 0.0f;
  float2 b = ((const float2*)bias)[lane];
  float ox = acc.x * inv + b.x;
  float oy = acc.y * inv + b.y;
  if (RELU) {
    ox = fmaxf(ox, 0.f);
    oy = fmaxf(oy, 0.f);
  }
  float2 r;
  r.x = ox;
  r.y = oy;
  ((float2*)(out + (size_t)w * DDIM))[lane] = r;
}

extern "C" void kernel_launch(void* const* d_in, const int* in_sizes, int n_in,
                              void* d_out, int out_size, void* d_ws, size_t ws_size,
                              hipStream_t stream) {
  const float* x = (const float*)d_in[0];
  const int* eidx = (const int*)d_in[1];
  const float* W1 = (const float*)d_in[2];
  const float* b1 = (const float*)d_in[3];
  const float* W2 = (const float*)d_in[4];
  const float* b2 = (const float*)d_in[5];
  const int nnz = in_sizes[1] / 2;
  const int n_nodes = in_sizes[0] / DDIM;
  const int* src = eidx;
  const int* dst = eidx + nnz;
  float* outf = (float*)d_out;

  char* ws = (char*)d_ws;
  size_t off = 0;
  auto carve = [&](size_t bytes) -> char* {
    char* p = ws + off;
    off += (bytes + 255) & ~(size_t)255;
    return p;
  };
  float* bufA = (float*)carve((size_t)N_NODES * DDIM * 4);      // X@W result
  float* he = (float*)carve((size_t)N_HEDGES * DDIM * 4);       // hyperedge features
  int* deg_e = (int*)carve((size_t)(N_HEDGES + N_NODES) * 4);   // contiguous for one memset
  int* deg_n = deg_e + N_HEDGES;
  int* offs_e = (int*)carve((size_t)(N_HEDGES + 1) * 4);
  int* offs_n = (int*)carve((size_t)(N_NODES + 1) * 4);
  int* cur_e = (int*)carve((size_t)N_HEDGES * 4);
  int* cur_n = (int*)carve((size_t)N_NODES * 4);
  int* adj_e = (int*)carve((size_t)nnz * 4);
  int* adj_n = (int*)carve((size_t)nnz * 4);

  hipMemsetAsync(deg_e, 0, (size_t)(N_HEDGES + N_NODES) * 4, stream);

  int ngrid = (nnz + 255) / 256;
  hist_deg<<<ngrid, 256, 0, stream>>>(src, dst, nnz, deg_e, deg_n);
  scan_csr<<<1, 1024, 0, stream>>>(deg_e, offs_e, cur_e, N_HEDGES);
  scan_csr<<<1, 1024, 0, stream>>>(deg_n, offs_n, cur_n, N_NODES);
  fill_csr<<<ngrid, 256, 0, stream>>>(src, dst, nnz, cur_e, cur_n, adj_e, adj_n);

  // ---- layer 1: h = relu(Dinv * A_n (Binv * A_e (x@W1)) + b1) -> stored in d_out ----
  gemm128<<<512, 256, 0, stream>>>(x, W1, bufA, n_nodes);
  seg_mean<<<(N_HEDGES + 3) / 4, 256, 0, stream>>>(bufA, offs_e, adj_e, he, N_HEDGES);
  seg_mean_bias<1><<<(N_NODES + 3) / 4, 256, 0, stream>>>(he, offs_n, adj_n, b1, outf, N_NODES);

  // ---- layer 2: out = Dinv * A_n (Binv * A_e (h@W2)) + b2 ----
  gemm128<<<512, 256, 0, stream>>>(outf, W2, bufA, n_nodes);
  seg_mean<<<(N_HEDGES + 3) / 4, 256, 0, stream>>>(bufA, offs_e, adj_e, he, N_HEDGES);
  seg_mean_bias<0><<<(N_NODES + 3) / 4, 256, 0, stream>>>(he, offs_n, adj_n, b2, outf, N_NODES);
}

// Round 2
// 492.613 us; speedup vs baseline: 1.2032x; 1.2032x over previous
//
#include <hip/hip_runtime.h>

#define N_NODES 50000
#define N_HEDGES 10000
#define DDIM 128

#define SCAN_BLK_ITEMS 4096  // 256 threads * 16 items

// ---------------- degree histogram ----------------
__global__ __launch_bounds__(256) void hist_deg(
    const int* __restrict__ src, const int* __restrict__ dst, int nnz,
    int* __restrict__ deg_e, int* __restrict__ deg_n) {
  int i = blockIdx.x * 256 + threadIdx.x;
  if (i < nnz) {
    atomicAdd(&deg_e[dst[i]], 1);
    atomicAdd(&deg_n[src[i]], 1);
  }
}

// ---------------- hierarchical scan, pass 1: per-block sums ----------------
// blocks [0, nb_e) cover deg_e, blocks [nb_e, nb_tot) cover deg_n
__global__ __launch_bounds__(256) void scan_pass1(
    const int* __restrict__ deg_e, const int* __restrict__ deg_n,
    int* __restrict__ aux, int nb_e) {
  int b = blockIdx.x;
  const int* deg;
  int n, chunk;
  if (b < nb_e) { deg = deg_e; n = N_HEDGES; chunk = b; }
  else          { deg = deg_n; n = N_NODES;  chunk = b - nb_e; }
  int base = chunk * SCAN_BLK_ITEMS + threadIdx.x * 16;
  int s = 0;
  if (base + 16 <= n) {
    const int4* p = (const int4*)(deg + base);
#pragma unroll
    for (int i = 0; i < 4; ++i) { int4 v = p[i]; s += v.x + v.y + v.z + v.w; }
  } else {
    for (int i = 0; i < 16; ++i) { int idx = base + i; if (idx < n) s += deg[idx]; }
  }
  __shared__ int red[256];
  red[threadIdx.x] = s;
  __syncthreads();
  for (int o = 128; o > 0; o >>= 1) {
    if (threadIdx.x < o) red[threadIdx.x] += red[threadIdx.x + o];
    __syncthreads();
  }
  if (threadIdx.x == 0) aux[b] = red[0];
}

// ---------------- pass 2: serial exclusive scan of block sums (tiny) ----------------
__global__ __launch_bounds__(64) void scan_pass2(
    int* __restrict__ aux, int nb_e, int nb_tot,
    int* __restrict__ offs_e, int* __restrict__ offs_n, int n_e, int n_n) {
  if (threadIdx.x == 0) {
    int run = 0;
    for (int i = 0; i < nb_e; ++i) { int v = aux[i]; aux[i] = run; run += v; }
    offs_e[n_e] = run;
    run = 0;
    for (int i = nb_e; i < nb_tot; ++i) { int v = aux[i]; aux[i] = run; run += v; }
    offs_n[n_n] = run;
  }
}

// ---------------- pass 3: per-block exclusive scan + aux offset ----------------
__global__ __launch_bounds__(256) void scan_pass3(
    const int* __restrict__ deg_e, const int* __restrict__ deg_n,
    const int* __restrict__ aux, int nb_e,
    int* __restrict__ offs_e, int* __restrict__ offs_n,
    int* __restrict__ cur_e, int* __restrict__ cur_n) {
  int b = blockIdx.x;
  const int* deg;
  int n, chunk;
  int *offs, *cur;
  if (b < nb_e) { deg = deg_e; n = N_HEDGES; chunk = b;        offs = offs_e; cur = cur_e; }
  else          { deg = deg_n; n = N_NODES;  chunk = b - nb_e; offs = offs_n; cur = cur_n; }
  int base = chunk * SCAN_BLK_ITEMS + threadIdx.x * 16;
  int v[16];
  int s = 0;
  bool full = (base + 16 <= n);
  if (full) {
    const int4* p = (const int4*)(deg + base);
#pragma unroll
    for (int i = 0; i < 4; ++i) {
      int4 q = p[i];
      v[4 * i] = q.x; v[4 * i + 1] = q.y; v[4 * i + 2] = q.z; v[4 * i + 3] = q.w;
    }
  } else {
    for (int i = 0; i < 16; ++i) { int idx = base + i; v[i] = (idx < n) ? deg[idx] : 0; }
  }
#pragma unroll
  for (int i = 0; i < 16; ++i) { int t = v[i]; v[i] = s; s += t; }
  __shared__ int red[256];
  int t = threadIdx.x;
  red[t] = s;
  __syncthreads();
  for (int o = 1; o < 256; o <<= 1) {
    int u = (t >= o) ? red[t - o] : 0;
    __syncthreads();
    red[t] += u;
    __syncthreads();
  }
  int pre = (t == 0) ? 0 : red[t - 1];
  pre += aux[b];
  if (full) {
#pragma unroll
    for (int i = 0; i < 16; ++i) v[i] += pre;
    int4* o4 = (int4*)(offs + base);
    int4* c4 = (int4*)(cur + base);
#pragma unroll
    for (int i = 0; i < 4; ++i) {
      int4 q = {v[4 * i], v[4 * i + 1], v[4 * i + 2], v[4 * i + 3]};
      o4[i] = q;
      c4[i] = q;
    }
  } else {
    for (int i = 0; i < 16; ++i) {
      int idx = base + i;
      if (idx < n) { offs[idx] = v[i] + pre; cur[idx] = v[i] + pre; }
    }
  }
}

// ---------------- CSR fill ----------------
__global__ __launch_bounds__(256) void fill_csr(
    const int* __restrict__ src, const int* __restrict__ dst, int nnz,
    int* __restrict__ cur_e, int* __restrict__ cur_n,
    int* __restrict__ adj_e, int* __restrict__ adj_n) {
  int i = blockIdx.x * 256 + threadIdx.x;
  if (i < nnz) {
    int s = src[i], d = dst[i];
    adj_e[atomicAdd(&cur_e[d], 1)] = s;  // per hyperedge: list of src nodes
    adj_n[atomicAdd(&cur_n[s], 1)] = d;  // per node: list of hyperedges
  }
}

// ---------------- GEMM: Y[n_rows,128] = X[n_rows,128] * W[128,128] ----------------
#define ACC4(accv, xv)                                          \
  accv.x += xv.x * w0.x + xv.y * w1.x + xv.z * w2.x + xv.w * w3.x; \
  accv.y += xv.x * w0.y + xv.y * w1.y + xv.z * w2.y + xv.w * w3.y; \
  accv.z += xv.x * w0.z + xv.y * w1.z + xv.z * w2.z + xv.w * w3.z; \
  accv.w += xv.x * w0.w + xv.y * w1.w + xv.z * w2.w + xv.w * w3.w;

__global__ __launch_bounds__(256, 2) void gemm128(
    const float* __restrict__ X, const float* __restrict__ W,
    float* __restrict__ Y, int n_rows) {
  __shared__ float sW[128 * 128];  // 64 KB
  __shared__ float sX[32 * 128];   // 16 KB
  const int t = threadIdx.x;
  {
    const float4* W4 = (const float4*)W;
    float4* sW4w = (float4*)sW;
#pragma unroll
    for (int i = 0; i < 16; ++i) sW4w[t + 256 * i] = W4[t + 256 * i];
  }
  const int lane = t & 63;
  const int wid = t >> 6;
  const int cg = lane & 31;                       // cols [4cg, 4cg+4)
  const int row_in_blk = wid * 8 + (lane >> 5) * 4;  // 4 rows per thread
  const float4* sW4 = (const float4*)sW;

  for (int base = blockIdx.x * 32; base < n_rows; base += gridDim.x * 32) {
    __syncthreads();
    {
      const float4* X4 = (const float4*)(X + (size_t)base * DDIM);
      float4* sX4 = (float4*)sX;
      int limit4 = min(32, n_rows - base) * 32;
#pragma unroll
      for (int i = 0; i < 4; ++i) {
        int idx = t + 256 * i;
        if (idx < limit4) sX4[idx] = X4[idx];
      }
    }
    __syncthreads();
    float4 acc0 = {0, 0, 0, 0}, acc1 = {0, 0, 0, 0}, acc2 = {0, 0, 0, 0}, acc3 = {0, 0, 0, 0};
    const float4* x0 = (const float4*)(sX + (row_in_blk + 0) * DDIM);
    const float4* x1 = (const float4*)(sX + (row_in_blk + 1) * DDIM);
    const float4* x2 = (const float4*)(sX + (row_in_blk + 2) * DDIM);
    const float4* x3 = (const float4*)(sX + (row_in_blk + 3) * DDIM);
#pragma unroll 8
    for (int k4 = 0; k4 < 32; ++k4) {
      float4 w0 = sW4[(4 * k4 + 0) * 32 + cg];
      float4 w1 = sW4[(4 * k4 + 1) * 32 + cg];
      float4 w2 = sW4[(4 * k4 + 2) * 32 + cg];
      float4 w3 = sW4[(4 * k4 + 3) * 32 + cg];
      float4 xa = x0[k4], xb = x1[k4], xc = x2[k4], xd = x3[k4];
      ACC4(acc0, xa)
      ACC4(acc1, xb)
      ACC4(acc2, xc)
      ACC4(acc3, xd)
    }
    int r = base + row_in_blk;
    if (r + 0 < n_rows) ((float4*)(Y + (size_t)(r + 0) * DDIM))[cg] = acc0;
    if (r + 1 < n_rows) ((float4*)(Y + (size_t)(r + 1) * DDIM))[cg] = acc1;
    if (r + 2 < n_rows) ((float4*)(Y + (size_t)(r + 2) * DDIM))[cg] = acc2;
    if (r + 3 < n_rows) ((float4*)(Y + (size_t)(r + 3) * DDIM))[cg] = acc3;
  }
}

// ---------------- segment mean (one wave per segment, 128 cols via float2) ----------------
__global__ __launch_bounds__(256) void seg_mean(
    const float* __restrict__ rows, const int* __restrict__ offs,
    const int* __restrict__ adj, float* __restrict__ out, int n_seg) {
  int w = (int)((blockIdx.x * 256 + threadIdx.x) >> 6);
  int lane = threadIdx.x & 63;
  if (w >= n_seg) return;
  int beg = offs[w], end = offs[w + 1];
  float2 acc = {0.f, 0.f};
  int j = beg;
  for (; j + 2 <= end; j += 2) {
    int s0 = adj[j], s1 = adj[j + 1];
    float2 v0 = ((const float2*)(rows + (size_t)s0 * DDIM))[lane];
    float2 v1 = ((const float2*)(rows + (size_t)s1 * DDIM))[lane];
    acc.x += v0.x + v1.x;
    acc.y += v0.y + v1.y;
  }
  if (j < end) {
    int s0 = adj[j];
    float2 v0 = ((const float2*)(rows + (size_t)s0 * DDIM))[lane];
    acc.x += v0.x;
    acc.y += v0.y;
  }
  float inv = (end > beg) ? 1.0f / (float)(end - beg) : 0.0f;
  float2 r;
  r.x = acc.x * inv;
  r.y = acc.y * inv;
  ((float2*)(out + (size_t)w * DDIM))[lane] = r;
}

template <int RELU>
__global__ __launch_bounds__(256) void seg_mean_bias(
    const float* __restrict__ rows, const int* __restrict__ offs,
    const int* __restrict__ adj, const float* __restrict__ bias,
    float* __restrict__ out, int n_seg) {
  int w = (int)((blockIdx.x * 256 + threadIdx.x) >> 6);
  int lane = threadIdx.x & 63;
  if (w >= n_seg) return;
  int beg = offs[w], end = offs[w + 1];
  float2 acc = {0.f, 0.f};
  int j = beg;
  for (; j + 2 <= end; j += 2) {
    int s0 = adj[j], s1 = adj[j + 1];
    float2 v0 = ((const float2*)(rows + (size_t)s0 * DDIM))[lane];
    float2 v1 = ((const float2*)(rows + (size_t)s1 * DDIM))[lane];
    acc.x += v0.x + v1.x;
    acc.y += v0.y + v1.y;
  }
  if (j < end) {
    int s0 = adj[j];
    float2 v0 = ((const float2*)(rows + (size_t)s0 * DDIM))[lane];
    acc.x += v0.x;
    acc.y += v0.y;
  }
  float inv = (end > beg) ? 1.0f / (float)(end - beg) : 0.0f;
  float2 b = ((const float2*)bias)[lane];
  float ox = acc.x * inv + b.x;
  float oy = acc.y * inv + b.y;
  if (RELU) {
    ox = fmaxf(ox, 0.f);
    oy = fmaxf(oy, 0.f);
  }
  float2 r;
  r.x = ox;
  r.y = oy;
  ((float2*)(out + (size_t)w * DDIM))[lane] = r;
}

extern "C" void kernel_launch(void* const* d_in, const int* in_sizes, int n_in,
                              void* d_out, int out_size, void* d_ws, size_t ws_size,
                              hipStream_t stream) {
  const float* x = (const float*)d_in[0];
  const int* eidx = (const int*)d_in[1];
  const float* W1 = (const float*)d_in[2];
  const float* b1 = (const float*)d_in[3];
  const float* W2 = (const float*)d_in[4];
  const float* b2 = (const float*)d_in[5];
  const int nnz = in_sizes[1] / 2;
  const int n_nodes = in_sizes[0] / DDIM;
  const int* src = eidx;
  const int* dst = eidx + nnz;
  float* outf = (float*)d_out;

  char* ws = (char*)d_ws;
  size_t off = 0;
  auto carve = [&](size_t bytes) -> char* {
    char* p = ws + off;
    off += (bytes + 255) & ~(size_t)255;
    return p;
  };
  float* bufA = (float*)carve((size_t)N_NODES * DDIM * 4);      // X@W result
  float* he = (float*)carve((size_t)N_HEDGES * DDIM * 4);       // hyperedge features
  int* deg_e = (int*)carve((size_t)(N_HEDGES + N_NODES) * 4);   // contiguous for one memset
  int* deg_n = deg_e + N_HEDGES;
  int* offs_e = (int*)carve((size_t)(N_HEDGES + 1) * 4);
  int* offs_n = (int*)carve((size_t)(N_NODES + 1) * 4);
  int* cur_e = (int*)carve((size_t)N_HEDGES * 4);
  int* cur_n = (int*)carve((size_t)N_NODES * 4);
  int* adj_e = (int*)carve((size_t)nnz * 4);
  int* adj_n = (int*)carve((size_t)nnz * 4);
  int* aux = (int*)carve(64 * 4);

  hipMemsetAsync(deg_e, 0, (size_t)(N_HEDGES + N_NODES) * 4, stream);

  const int NB_E = (N_HEDGES + SCAN_BLK_ITEMS - 1) / SCAN_BLK_ITEMS;  // 3
  const int NB_N = (N_NODES + SCAN_BLK_ITEMS - 1) / SCAN_BLK_ITEMS;   // 13
  const int NB_TOT = NB_E + NB_N;                                     // 16

  int ngrid = (nnz + 255) / 256;
  hist_deg<<<ngrid, 256, 0, stream>>>(src, dst, nnz, deg_e, deg_n);
  scan_pass1<<<NB_TOT, 256, 0, stream>>>(deg_e, deg_n, aux, NB_E);
  scan_pass2<<<1, 64, 0, stream>>>(aux, NB_E, NB_TOT, offs_e, offs_n, N_HEDGES, N_NODES);
  scan_pass3<<<NB_TOT, 256, 0, stream>>>(deg_e, deg_n, aux, NB_E, offs_e, offs_n, cur_e, cur_n);
  fill_csr<<<ngrid, 256, 0, stream>>>(src, dst, nnz, cur_e, cur_n, adj_e, adj_n);

  // ---- layer 1: h = relu(Dinv * A_n (Binv * A_e (x@W1)) + b1) -> stored in d_out ----
  gemm128<<<512, 256, 0, stream>>>(x, W1, bufA, n_nodes);
  seg_mean<<<(N_HEDGES + 3) / 4, 256, 0, stream>>>(bufA, offs_e, adj_e, he, N_HEDGES);
  seg_mean_bias<1><<<(N_NODES + 3) / 4, 256, 0, stream>>>(he, offs_n, adj_n, b1, outf, N_NODES);

  // ---- layer 2: out = Dinv * A_n (Binv * A_e (h@W2)) + b2 ----
  gemm128<<<512, 256, 0, stream>>>(outf, W2, bufA, n_nodes);
  seg_mean<<<(N_HEDGES + 3) / 4, 256, 0, stream>>>(bufA, offs_e, adj_e, he, N_HEDGES);
  seg_mean_bias<0><<<(N_NODES + 3) / 4, 256, 0, stream>>>(he, offs_n, adj_n, b2, outf, N_NODES);
}

// Round 4
// 480.855 us; speedup vs baseline: 1.2327x; 1.0245x over previous
//
#include <hip/hip_runtime.h>

#define N_NODES 50000
#define N_HEDGES 10000
#define DDIM 128

#define SCAN_BLK_ITEMS 4096  // 256 threads * 16 items
#define NXCD 8

// ---------------- degree histogram, XCD-range-partitioned ----------------
// Block group g = blockIdx&7 (round-robin XCD heuristic) owns
// deg_e[g*1250 .. +1250) and deg_n[g*6250 .. +6250). Each group streams the
// whole edge list; commits only its range -> all writes/atomics to a given
// cache line come from one XCD, so lines coalesce in that XCD's L2.
__global__ __launch_bounds__(256) void hist_deg_grp(
    const int* __restrict__ src, const int* __restrict__ dst, int nnz,
    int* __restrict__ deg_e, int* __restrict__ deg_n) {
  const int g = blockIdx.x & (NXCD - 1);
  const int bg = blockIdx.x >> 3;
  const int bpg = gridDim.x >> 3;
  const int e_lo = g * (N_HEDGES / NXCD), e_hi = e_lo + N_HEDGES / NXCD;
  const int n_lo = g * (N_NODES / NXCD), n_hi = n_lo + N_NODES / NXCD;
  const int stride = bpg * 256 * 4;
  for (int i = (bg * 256 + (int)threadIdx.x) * 4; i < nnz; i += stride) {
    if (i + 4 <= nnz) {
      int4 s4 = *(const int4*)(src + i);
      int4 d4 = *(const int4*)(dst + i);
      if (d4.x >= e_lo && d4.x < e_hi) atomicAdd(&deg_e[d4.x], 1);
      if (d4.y >= e_lo && d4.y < e_hi) atomicAdd(&deg_e[d4.y], 1);
      if (d4.z >= e_lo && d4.z < e_hi) atomicAdd(&deg_e[d4.z], 1);
      if (d4.w >= e_lo && d4.w < e_hi) atomicAdd(&deg_e[d4.w], 1);
      if (s4.x >= n_lo && s4.x < n_hi) atomicAdd(&deg_n[s4.x], 1);
      if (s4.y >= n_lo && s4.y < n_hi) atomicAdd(&deg_n[s4.y], 1);
      if (s4.z >= n_lo && s4.z < n_hi) atomicAdd(&deg_n[s4.z], 1);
      if (s4.w >= n_lo && s4.w < n_hi) atomicAdd(&deg_n[s4.w], 1);
    } else {
      for (int j = i; j < nnz; ++j) {
        int d = dst[j], s = src[j];
        if (d >= e_lo && d < e_hi) atomicAdd(&deg_e[d], 1);
        if (s >= n_lo && s < n_hi) atomicAdd(&deg_n[s], 1);
      }
    }
  }
}

// ---------------- hierarchical scan, pass 1: per-block sums ----------------
__global__ __launch_bounds__(256) void scan_pass1(
    const int* __restrict__ deg_e, const int* __restrict__ deg_n,
    int* __restrict__ aux, int nb_e) {
  int b = blockIdx.x;
  const int* deg;
  int n, chunk;
  if (b < nb_e) { deg = deg_e; n = N_HEDGES; chunk = b; }
  else          { deg = deg_n; n = N_NODES;  chunk = b - nb_e; }
  int base = chunk * SCAN_BLK_ITEMS + threadIdx.x * 16;
  int s = 0;
  if (base + 16 <= n) {
    const int4* p = (const int4*)(deg + base);
#pragma unroll
    for (int i = 0; i < 4; ++i) { int4 v = p[i]; s += v.x + v.y + v.z + v.w; }
  } else {
    for (int i = 0; i < 16; ++i) { int idx = base + i; if (idx < n) s += deg[idx]; }
  }
  __shared__ int red[256];
  red[threadIdx.x] = s;
  __syncthreads();
  for (int o = 128; o > 0; o >>= 1) {
    if (threadIdx.x < o) red[threadIdx.x] += red[threadIdx.x + o];
    __syncthreads();
  }
  if (threadIdx.x == 0) aux[b] = red[0];
}

// ---------------- pass 2: serial exclusive scan of block sums (tiny) ----------------
__global__ __launch_bounds__(64) void scan_pass2(
    int* __restrict__ aux, int nb_e, int nb_tot,
    int* __restrict__ offs_e, int* __restrict__ offs_n, int n_e, int n_n) {
  if (threadIdx.x == 0) {
    int run = 0;
    for (int i = 0; i < nb_e; ++i) { int v = aux[i]; aux[i] = run; run += v; }
    offs_e[n_e] = run;
    run = 0;
    for (int i = nb_e; i < nb_tot; ++i) { int v = aux[i]; aux[i] = run; run += v; }
    offs_n[n_n] = run;
  }
}

// ---------------- pass 3: per-block exclusive scan + aux offset ----------------
__global__ __launch_bounds__(256) void scan_pass3(
    const int* __restrict__ deg_e, const int* __restrict__ deg_n,
    const int* __restrict__ aux, int nb_e,
    int* __restrict__ offs_e, int* __restrict__ offs_n,
    int* __restrict__ cur_e, int* __restrict__ cur_n) {
  int b = blockIdx.x;
  const int* deg;
  int n, chunk;
  int *offs, *cur;
  if (b < nb_e) { deg = deg_e; n = N_HEDGES; chunk = b;        offs = offs_e; cur = cur_e; }
  else          { deg = deg_n; n = N_NODES;  chunk = b - nb_e; offs = offs_n; cur = cur_n; }
  int base = chunk * SCAN_BLK_ITEMS + threadIdx.x * 16;
  int v[16];
  int s = 0;
  bool full = (base + 16 <= n);
  if (full) {
    const int4* p = (const int4*)(deg + base);
#pragma unroll
    for (int i = 0; i < 4; ++i) {
      int4 q = p[i];
      v[4 * i] = q.x; v[4 * i + 1] = q.y; v[4 * i + 2] = q.z; v[4 * i + 3] = q.w;
    }
  } else {
    for (int i = 0; i < 16; ++i) { int idx = base + i; v[i] = (idx < n) ? deg[idx] : 0; }
  }
#pragma unroll
  for (int i = 0; i < 16; ++i) { int t = v[i]; v[i] = s; s += t; }
  __shared__ int red[256];
  int t = threadIdx.x;
  red[t] = s;
  __syncthreads();
  for (int o = 1; o < 256; o <<= 1) {
    int u = (t >= o) ? red[t - o] : 0;
    __syncthreads();
    red[t] += u;
    __syncthreads();
  }
  int pre = (t == 0) ? 0 : red[t - 1];
  pre += aux[b];
  if (full) {
#pragma unroll
    for (int i = 0; i < 16; ++i) v[i] += pre;
    int4* o4 = (int4*)(offs + base);
    int4* c4 = (int4*)(cur + base);
#pragma unroll
    for (int i = 0; i < 4; ++i) {
      int4 q = {v[4 * i], v[4 * i + 1], v[4 * i + 2], v[4 * i + 3]};
      o4[i] = q;
      c4[i] = q;
    }
  } else {
    for (int i = 0; i < 16; ++i) {
      int idx = base + i;
      if (idx < n) { offs[idx] = v[i] + pre; cur[idx] = v[i] + pre; }
    }
  }
}

// ---------------- CSR fill, XCD-range-partitioned ----------------
__global__ __launch_bounds__(256) void fill_csr_grp(
    const int* __restrict__ src, const int* __restrict__ dst, int nnz,
    int* __restrict__ cur_e, int* __restrict__ cur_n,
    int* __restrict__ adj_e, int* __restrict__ adj_n) {
  const int g = blockIdx.x & (NXCD - 1);
  const int bg = blockIdx.x >> 3;
  const int bpg = gridDim.x >> 3;
  const int e_lo = g * (N_HEDGES / NXCD), e_hi = e_lo + N_HEDGES / NXCD;
  const int n_lo = g * (N_NODES / NXCD), n_hi = n_lo + N_NODES / NXCD;
  const int stride = bpg * 256 * 4;
  for (int i = (bg * 256 + (int)threadIdx.x) * 4; i < nnz; i += stride) {
    if (i + 4 <= nnz) {
      int4 s4 = *(const int4*)(src + i);
      int4 d4 = *(const int4*)(dst + i);
      if (d4.x >= e_lo && d4.x < e_hi) adj_e[atomicAdd(&cur_e[d4.x], 1)] = s4.x;
      if (d4.y >= e_lo && d4.y < e_hi) adj_e[atomicAdd(&cur_e[d4.y], 1)] = s4.y;
      if (d4.z >= e_lo && d4.z < e_hi) adj_e[atomicAdd(&cur_e[d4.z], 1)] = s4.z;
      if (d4.w >= e_lo && d4.w < e_hi) adj_e[atomicAdd(&cur_e[d4.w], 1)] = s4.w;
      if (s4.x >= n_lo && s4.x < n_hi) adj_n[atomicAdd(&cur_n[s4.x], 1)] = d4.x;
      if (s4.y >= n_lo && s4.y < n_hi) adj_n[atomicAdd(&cur_n[s4.y], 1)] = d4.y;
      if (s4.z >= n_lo && s4.z < n_hi) adj_n[atomicAdd(&cur_n[s4.z], 1)] = d4.z;
      if (s4.w >= n_lo && s4.w < n_hi) adj_n[atomicAdd(&cur_n[s4.w], 1)] = d4.w;
    } else {
      for (int j = i; j < nnz; ++j) {
        int d = dst[j], s = src[j];
        if (d >= e_lo && d < e_hi) adj_e[atomicAdd(&cur_e[d], 1)] = s;
        if (s >= n_lo && s < n_hi) adj_n[atomicAdd(&cur_n[s], 1)] = d;
      }
    }
  }
}

// ---------------- GEMM: Y[n_rows,128] = X[n_rows,128] * W[128,128] ----------------
#define ACC4(accv, xv)                                          \
  accv.x += xv.x * w0.x + xv.y * w1.x + xv.z * w2.x + xv.w * w3.x; \
  accv.y += xv.x * w0.y + xv.y * w1.y + xv.z * w2.y + xv.w * w3.y; \
  accv.z += xv.x * w0.z + xv.y * w1.z + xv.z * w2.z + xv.w * w3.z; \
  accv.w += xv.x * w0.w + xv.y * w1.w + xv.z * w2.w + xv.w * w3.w;

__global__ __launch_bounds__(256, 2) void gemm128(
    const float* __restrict__ X, const float* __restrict__ W,
    float* __restrict__ Y, int n_rows) {
  __shared__ float sW[128 * 128];  // 64 KB
  __shared__ float sX[32 * 128];   // 16 KB
  const int t = threadIdx.x;
  {
    const float4* W4 = (const float4*)W;
    float4* sW4w = (float4*)sW;
#pragma unroll
    for (int i = 0; i < 16; ++i) sW4w[t + 256 * i] = W4[t + 256 * i];
  }
  const int lane = t & 63;
  const int wid = t >> 6;
  const int cg = lane & 31;                       // cols [4cg, 4cg+4)
  const int row_in_blk = wid * 8 + (lane >> 5) * 4;  // 4 rows per thread
  const float4* sW4 = (const float4*)sW;

  for (int base = blockIdx.x * 32; base < n_rows; base += gridDim.x * 32) {
    __syncthreads();
    {
      const float4* X4 = (const float4*)(X + (size_t)base * DDIM);
      float4* sX4 = (float4*)sX;
      int limit4 = min(32, n_rows - base) * 32;
#pragma unroll
      for (int i = 0; i < 4; ++i) {
        int idx = t + 256 * i;
        if (idx < limit4) sX4[idx] = X4[idx];
      }
    }
    __syncthreads();
    float4 acc0 = {0, 0, 0, 0}, acc1 = {0, 0, 0, 0}, acc2 = {0, 0, 0, 0}, acc3 = {0, 0, 0, 0};
    const float4* x0 = (const float4*)(sX + (row_in_blk + 0) * DDIM);
    const float4* x1 = (const float4*)(sX + (row_in_blk + 1) * DDIM);
    const float4* x2 = (const float4*)(sX + (row_in_blk + 2) * DDIM);
    const float4* x3 = (const float4*)(sX + (row_in_blk + 3) * DDIM);
#pragma unroll 8
    for (int k4 = 0; k4 < 32; ++k4) {
      float4 w0 = sW4[(4 * k4 + 0) * 32 + cg];
      float4 w1 = sW4[(4 * k4 + 1) * 32 + cg];
      float4 w2 = sW4[(4 * k4 + 2) * 32 + cg];
      float4 w3 = sW4[(4 * k4 + 3) * 32 + cg];
      float4 xa = x0[k4], xb = x1[k4], xc = x2[k4], xd = x3[k4];
      ACC4(acc0, xa)
      ACC4(acc1, xb)
      ACC4(acc2, xc)
      ACC4(acc3, xd)
    }
    int r = base + row_in_blk;
    if (r + 0 < n_rows) ((float4*)(Y + (size_t)(r + 0) * DDIM))[cg] = acc0;
    if (r + 1 < n_rows) ((float4*)(Y + (size_t)(r + 1) * DDIM))[cg] = acc1;
    if (r + 2 < n_rows) ((float4*)(Y + (size_t)(r + 2) * DDIM))[cg] = acc2;
    if (r + 3 < n_rows) ((float4*)(Y + (size_t)(r + 3) * DDIM))[cg] = acc3;
  }
}

// ---------------- segment mean (one wave per segment, 128 cols via float2) ----------------
__global__ __launch_bounds__(256) void seg_mean(
    const float* __restrict__ rows, const int* __restrict__ offs,
    const int* __restrict__ adj, float* __restrict__ out, int n_seg) {
  int w = (int)((blockIdx.x * 256 + threadIdx.x) >> 6);
  int lane = threadIdx.x & 63;
  if (w >= n_seg) return;
  int beg = offs[w], end = offs[w + 1];
  float2 acc = {0.f, 0.f};
  int j = beg;
  for (; j + 2 <= end; j += 2) {
    int s0 = adj[j], s1 = adj[j + 1];
    float2 v0 = ((const float2*)(rows + (size_t)s0 * DDIM))[lane];
    float2 v1 = ((const float2*)(rows + (size_t)s1 * DDIM))[lane];
    acc.x += v0.x + v1.x;
    acc.y += v0.y + v1.y;
  }
  if (j < end) {
    int s0 = adj[j];
    float2 v0 = ((const float2*)(rows + (size_t)s0 * DDIM))[lane];
    acc.x += v0.x;
    acc.y += v0.y;
  }
  float inv = (end > beg) ? 1.0f / (float)(end - beg) : 0.0f;
  float2 r;
  r.x = acc.x * inv;
  r.y = acc.y * inv;
  ((float2*)(out + (size_t)w * DDIM))[lane] = r;
}

template <int RELU>
__global__ __launch_bounds__(256) void seg_mean_bias(
    const float* __restrict__ rows, const int* __restrict__ offs,
    const int* __restrict__ adj, const float* __restrict__ bias,
    float* __restrict__ out, int n_seg) {
  int w = (int)((blockIdx.x * 256 + threadIdx.x) >> 6);
  int lane = threadIdx.x & 63;
  if (w >= n_seg) return;
  int beg = offs[w], end = offs[w + 1];
  float2 acc = {0.f, 0.f};
  int j = beg;
  for (; j + 2 <= end; j += 2) {
    int s0 = adj[j], s1 = adj[j + 1];
    float2 v0 = ((const float2*)(rows + (size_t)s0 * DDIM))[lane];
    float2 v1 = ((const float2*)(rows + (size_t)s1 * DDIM))[lane];
    acc.x += v0.x + v1.x;
    acc.y += v0.y + v1.y;
  }
  if (j < end) {
    int s0 = adj[j];
    float2 v0 = ((const float2*)(rows + (size_t)s0 * DDIM))[lane];
    acc.x += v0.x;
    acc.y += v0.y;
  }
  float inv = (end > beg) ? 1.0f / (float)(end - beg) : 0.0f;
  float2 b = ((const float2*)bias)[lane];
  float ox = acc.x * inv + b.x;
  float oy = acc.y * inv + b.y;
  if (RELU) {
    ox = fmaxf(ox, 0.f);
    oy = fmaxf(oy, 0.f);
  }
  float2 r;
  r.x = ox;
  r.y = oy;
  ((float2*)(out + (size_t)w * DDIM))[lane] = r;
}

extern "C" void kernel_launch(void* const* d_in, const int* in_sizes, int n_in,
                              void* d_out, int out_size, void* d_ws, size_t ws_size,
                              hipStream_t stream) {
  const float* x = (const float*)d_in[0];
  const int* eidx = (const int*)d_in[1];
  const float* W1 = (const float*)d_in[2];
  const float* b1 = (const float*)d_in[3];
  const float* W2 = (const float*)d_in[4];
  const float* b2 = (const float*)d_in[5];
  const int nnz = in_sizes[1] / 2;
  const int n_nodes = in_sizes[0] / DDIM;
  const int* src = eidx;
  const int* dst = eidx + nnz;
  float* outf = (float*)d_out;

  char* ws = (char*)d_ws;
  size_t off = 0;
  auto carve = [&](size_t bytes) -> char* {
    char* p = ws + off;
    off += (bytes + 255) & ~(size_t)255;
    return p;
  };
  float* bufA = (float*)carve((size_t)N_NODES * DDIM * 4);      // X@W result
  float* he = (float*)carve((size_t)N_HEDGES * DDIM * 4);       // hyperedge features
  int* deg_e = (int*)carve((size_t)(N_HEDGES + N_NODES) * 4);   // contiguous for one memset
  int* deg_n = deg_e + N_HEDGES;
  int* offs_e = (int*)carve((size_t)(N_HEDGES + 1) * 4);
  int* offs_n = (int*)carve((size_t)(N_NODES + 1) * 4);
  int* cur_e = (int*)carve((size_t)N_HEDGES * 4);
  int* cur_n = (int*)carve((size_t)N_NODES * 4);
  int* adj_e = (int*)carve((size_t)nnz * 4);
  int* adj_n = (int*)carve((size_t)nnz * 4);
  int* aux = (int*)carve(64 * 4);

  hipMemsetAsync(deg_e, 0, (size_t)(N_HEDGES + N_NODES) * 4, stream);

  const int NB_E = (N_HEDGES + SCAN_BLK_ITEMS - 1) / SCAN_BLK_ITEMS;  // 3
  const int NB_N = (N_NODES + SCAN_BLK_ITEMS - 1) / SCAN_BLK_ITEMS;   // 13
  const int NB_TOT = NB_E + NB_N;                                     // 16

  hist_deg_grp<<<1024, 256, 0, stream>>>(src, dst, nnz, deg_e, deg_n);
  scan_pass1<<<NB_TOT, 256, 0, stream>>>(deg_e, deg_n, aux, NB_E);
  scan_pass2<<<1, 64, 0, stream>>>(aux, NB_E, NB_TOT, offs_e, offs_n, N_HEDGES, N_NODES);
  scan_pass3<<<NB_TOT, 256, 0, stream>>>(deg_e, deg_n, aux, NB_E, offs_e, offs_n, cur_e, cur_n);
  fill_csr_grp<<<1024, 256, 0, stream>>>(src, dst, nnz, cur_e, cur_n, adj_e, adj_n);

  // ---- layer 1: h = relu(Dinv * A_n (Binv * A_e (x@W1)) + b1) -> stored in d_out ----
  gemm128<<<512, 256, 0, stream>>>(x, W1, bufA, n_nodes);
  seg_mean<<<(N_HEDGES + 3) / 4, 256, 0, stream>>>(bufA, offs_e, adj_e, he, N_HEDGES);
  seg_mean_bias<1><<<(N_NODES + 3) / 4, 256, 0, stream>>>(he, offs_n, adj_n, b1, outf, N_NODES);

  // ---- layer 2: out = Dinv * A_n (Binv * A_e (h@W2)) + b2 ----
  gemm128<<<512, 256, 0, stream>>>(outf, W2, bufA, n_nodes);
  seg_mean<<<(N_HEDGES + 3) / 4, 256, 0, stream>>>(bufA, offs_e, adj_e, he, N_HEDGES);
  seg_mean_bias<0><<<(N_NODES + 3) / 4, 256, 0, stream>>>(he, offs_n, adj_n, b2, outf, N_NODES);
}

// Round 5
// 435.352 us; speedup vs baseline: 1.3615x; 1.1045x over previous
//
#include <hip/hip_runtime.h>

#define N_NODES 50000
#define N_HEDGES 10000
#define DDIM 128

#define SCAN_BLK_ITEMS 4096  // 256 threads * 16 items
#define NXCD 8

typedef int v4i __attribute__((ext_vector_type(4)));
__device__ __forceinline__ v4i ntload4(const int* p) {
  return __builtin_nontemporal_load((const v4i*)p);
}

// ---------------- degree histogram, XCD-range-partitioned ----------------
// Block group g = blockIdx&7 (round-robin XCD heuristic) owns
// deg_e[g*1250 .. +1250) and deg_n[g*6250 .. +6250). Each group streams the
// whole edge list (non-temporal, so the stream doesn't thrash L2) and commits
// only its range -> all writes to a given cache line come from one XCD and
// the dirty lines survive in L2 until full.
__global__ __launch_bounds__(256) void hist_deg_grp(
    const int* __restrict__ src, const int* __restrict__ dst, int nnz,
    int* __restrict__ deg_e, int* __restrict__ deg_n) {
  const int g = blockIdx.x & (NXCD - 1);
  const int bg = blockIdx.x >> 3;
  const int bpg = gridDim.x >> 3;
  const int e_lo = g * (N_HEDGES / NXCD), e_hi = e_lo + N_HEDGES / NXCD;
  const int n_lo = g * (N_NODES / NXCD), n_hi = n_lo + N_NODES / NXCD;
  const int stride = bpg * 256 * 4;
  for (int i = (bg * 256 + (int)threadIdx.x) * 4; i < nnz; i += stride) {
    if (i + 4 <= nnz) {
      v4i s4 = ntload4(src + i);
      v4i d4 = ntload4(dst + i);
      if (d4.x >= e_lo && d4.x < e_hi) atomicAdd(&deg_e[d4.x], 1);
      if (d4.y >= e_lo && d4.y < e_hi) atomicAdd(&deg_e[d4.y], 1);
      if (d4.z >= e_lo && d4.z < e_hi) atomicAdd(&deg_e[d4.z], 1);
      if (d4.w >= e_lo && d4.w < e_hi) atomicAdd(&deg_e[d4.w], 1);
      if (s4.x >= n_lo && s4.x < n_hi) atomicAdd(&deg_n[s4.x], 1);
      if (s4.y >= n_lo && s4.y < n_hi) atomicAdd(&deg_n[s4.y], 1);
      if (s4.z >= n_lo && s4.z < n_hi) atomicAdd(&deg_n[s4.z], 1);
      if (s4.w >= n_lo && s4.w < n_hi) atomicAdd(&deg_n[s4.w], 1);
    } else {
      for (int j = i; j < nnz; ++j) {
        int d = dst[j], s = src[j];
        if (d >= e_lo && d < e_hi) atomicAdd(&deg_e[d], 1);
        if (s >= n_lo && s < n_hi) atomicAdd(&deg_n[s], 1);
      }
    }
  }
}

// ---------------- hierarchical scan, pass 1: per-block sums ----------------
__global__ __launch_bounds__(256) void scan_pass1(
    const int* __restrict__ deg_e, const int* __restrict__ deg_n,
    int* __restrict__ aux, int nb_e) {
  int b = blockIdx.x;
  const int* deg;
  int n, chunk;
  if (b < nb_e) { deg = deg_e; n = N_HEDGES; chunk = b; }
  else          { deg = deg_n; n = N_NODES;  chunk = b - nb_e; }
  int base = chunk * SCAN_BLK_ITEMS + threadIdx.x * 16;
  int s = 0;
  if (base + 16 <= n) {
    const int4* p = (const int4*)(deg + base);
#pragma unroll
    for (int i = 0; i < 4; ++i) { int4 v = p[i]; s += v.x + v.y + v.z + v.w; }
  } else {
    for (int i = 0; i < 16; ++i) { int idx = base + i; if (idx < n) s += deg[idx]; }
  }
  __shared__ int red[256];
  red[threadIdx.x] = s;
  __syncthreads();
  for (int o = 128; o > 0; o >>= 1) {
    if (threadIdx.x < o) red[threadIdx.x] += red[threadIdx.x + o];
    __syncthreads();
  }
  if (threadIdx.x == 0) aux[b] = red[0];
}

// ---------------- pass 2: serial exclusive scan of block sums (tiny) ----------------
__global__ __launch_bounds__(64) void scan_pass2(
    int* __restrict__ aux, int nb_e, int nb_tot,
    int* __restrict__ offs_e, int* __restrict__ offs_n, int n_e, int n_n) {
  if (threadIdx.x == 0) {
    int run = 0;
    for (int i = 0; i < nb_e; ++i) { int v = aux[i]; aux[i] = run; run += v; }
    offs_e[n_e] = run;
    run = 0;
    for (int i = nb_e; i < nb_tot; ++i) { int v = aux[i]; aux[i] = run; run += v; }
    offs_n[n_n] = run;
  }
}

// ---------------- pass 3: per-block exclusive scan + aux offset ----------------
__global__ __launch_bounds__(256) void scan_pass3(
    const int* __restrict__ deg_e, const int* __restrict__ deg_n,
    const int* __restrict__ aux, int nb_e,
    int* __restrict__ offs_e, int* __restrict__ offs_n,
    int* __restrict__ cur_e, int* __restrict__ cur_n) {
  int b = blockIdx.x;
  const int* deg;
  int n, chunk;
  int *offs, *cur;
  if (b < nb_e) { deg = deg_e; n = N_HEDGES; chunk = b;        offs = offs_e; cur = cur_e; }
  else          { deg = deg_n; n = N_NODES;  chunk = b - nb_e; offs = offs_n; cur = cur_n; }
  int base = chunk * SCAN_BLK_ITEMS + threadIdx.x * 16;
  int v[16];
  int s = 0;
  bool full = (base + 16 <= n);
  if (full) {
    const int4* p = (const int4*)(deg + base);
#pragma unroll
    for (int i = 0; i < 4; ++i) {
      int4 q = p[i];
      v[4 * i] = q.x; v[4 * i + 1] = q.y; v[4 * i + 2] = q.z; v[4 * i + 3] = q.w;
    }
  } else {
    for (int i = 0; i < 16; ++i) { int idx = base + i; v[i] = (idx < n) ? deg[idx] : 0; }
  }
#pragma unroll
  for (int i = 0; i < 16; ++i) { int t = v[i]; v[i] = s; s += t; }
  __shared__ int red[256];
  int t = threadIdx.x;
  red[t] = s;
  __syncthreads();
  for (int o = 1; o < 256; o <<= 1) {
    int u = (t >= o) ? red[t - o] : 0;
    __syncthreads();
    red[t] += u;
    __syncthreads();
  }
  int pre = (t == 0) ? 0 : red[t - 1];
  pre += aux[b];
  if (full) {
#pragma unroll
    for (int i = 0; i < 16; ++i) v[i] += pre;
    int4* o4 = (int4*)(offs + base);
    int4* c4 = (int4*)(cur + base);
#pragma unroll
    for (int i = 0; i < 4; ++i) {
      int4 q = {v[4 * i], v[4 * i + 1], v[4 * i + 2], v[4 * i + 3]};
      o4[i] = q;
      c4[i] = q;
    }
  } else {
    for (int i = 0; i < 16; ++i) {
      int idx = base + i;
      if (idx < n) { offs[idx] = v[i] + pre; cur[idx] = v[i] + pre; }
    }
  }
}

// ---------------- CSR fill, XCD-range-partitioned, nt edge stream ----------------
__global__ __launch_bounds__(256) void fill_csr_grp(
    const int* __restrict__ src, const int* __restrict__ dst, int nnz,
    int* __restrict__ cur_e, int* __restrict__ cur_n,
    int* __restrict__ adj_e, int* __restrict__ adj_n) {
  const int g = blockIdx.x & (NXCD - 1);
  const int bg = blockIdx.x >> 3;
  const int bpg = gridDim.x >> 3;
  const int e_lo = g * (N_HEDGES / NXCD), e_hi = e_lo + N_HEDGES / NXCD;
  const int n_lo = g * (N_NODES / NXCD), n_hi = n_lo + N_NODES / NXCD;
  const int stride = bpg * 256 * 4;
  for (int i = (bg * 256 + (int)threadIdx.x) * 4; i < nnz; i += stride) {
    if (i + 4 <= nnz) {
      v4i s4 = ntload4(src + i);
      v4i d4 = ntload4(dst + i);
      if (d4.x >= e_lo && d4.x < e_hi) adj_e[atomicAdd(&cur_e[d4.x], 1)] = s4.x;
      if (d4.y >= e_lo && d4.y < e_hi) adj_e[atomicAdd(&cur_e[d4.y], 1)] = s4.y;
      if (d4.z >= e_lo && d4.z < e_hi) adj_e[atomicAdd(&cur_e[d4.z], 1)] = s4.z;
      if (d4.w >= e_lo && d4.w < e_hi) adj_e[atomicAdd(&cur_e[d4.w], 1)] = s4.w;
      if (s4.x >= n_lo && s4.x < n_hi) adj_n[atomicAdd(&cur_n[s4.x], 1)] = d4.x;
      if (s4.y >= n_lo && s4.y < n_hi) adj_n[atomicAdd(&cur_n[s4.y], 1)] = d4.y;
      if (s4.z >= n_lo && s4.z < n_hi) adj_n[atomicAdd(&cur_n[s4.z], 1)] = d4.z;
      if (s4.w >= n_lo && s4.w < n_hi) adj_n[atomicAdd(&cur_n[s4.w], 1)] = d4.w;
    } else {
      for (int j = i; j < nnz; ++j) {
        int d = dst[j], s = src[j];
        if (d >= e_lo && d < e_hi) adj_e[atomicAdd(&cur_e[d], 1)] = s;
        if (s >= n_lo && s < n_hi) adj_n[atomicAdd(&cur_n[s], 1)] = d;
      }
    }
  }
}

// ---------------- GEMM: Y[n_rows,128] = X[n_rows,128] * W[128,128] ----------------
#define ACC4(accv, xv)                                          \
  accv.x += xv.x * w0.x + xv.y * w1.x + xv.z * w2.x + xv.w * w3.x; \
  accv.y += xv.x * w0.y + xv.y * w1.y + xv.z * w2.y + xv.w * w3.y; \
  accv.z += xv.x * w0.z + xv.y * w1.z + xv.z * w2.z + xv.w * w3.z; \
  accv.w += xv.x * w0.w + xv.y * w1.w + xv.z * w2.w + xv.w * w3.w;

__global__ __launch_bounds__(256, 2) void gemm128(
    const float* __restrict__ X, const float* __restrict__ W,
    float* __restrict__ Y, int n_rows) {
  __shared__ float sW[128 * 128];  // 64 KB
  __shared__ float sX[32 * 128];   // 16 KB
  const int t = threadIdx.x;
  {
    const float4* W4 = (const float4*)W;
    float4* sW4w = (float4*)sW;
#pragma unroll
    for (int i = 0; i < 16; ++i) sW4w[t + 256 * i] = W4[t + 256 * i];
  }
  const int lane = t & 63;
  const int wid = t >> 6;
  const int cg = lane & 31;                       // cols [4cg, 4cg+4)
  const int row_in_blk = wid * 8 + (lane >> 5) * 4;  // 4 rows per thread
  const float4* sW4 = (const float4*)sW;

  for (int base = blockIdx.x * 32; base < n_rows; base += gridDim.x * 32) {
    __syncthreads();
    {
      const float4* X4 = (const float4*)(X + (size_t)base * DDIM);
      float4* sX4 = (float4*)sX;
      int limit4 = min(32, n_rows - base) * 32;
#pragma unroll
      for (int i = 0; i < 4; ++i) {
        int idx = t + 256 * i;
        if (idx < limit4) sX4[idx] = X4[idx];
      }
    }
    __syncthreads();
    float4 acc0 = {0, 0, 0, 0}, acc1 = {0, 0, 0, 0}, acc2 = {0, 0, 0, 0}, acc3 = {0, 0, 0, 0};
    const float4* x0 = (const float4*)(sX + (row_in_blk + 0) * DDIM);
    const float4* x1 = (const float4*)(sX + (row_in_blk + 1) * DDIM);
    const float4* x2 = (const float4*)(sX + (row_in_blk + 2) * DDIM);
    const float4* x3 = (const float4*)(sX + (row_in_blk + 3) * DDIM);
#pragma unroll 8
    for (int k4 = 0; k4 < 32; ++k4) {
      float4 w0 = sW4[(4 * k4 + 0) * 32 + cg];
      float4 w1 = sW4[(4 * k4 + 1) * 32 + cg];
      float4 w2 = sW4[(4 * k4 + 2) * 32 + cg];
      float4 w3 = sW4[(4 * k4 + 3) * 32 + cg];
      float4 xa = x0[k4], xb = x1[k4], xc = x2[k4], xd = x3[k4];
      ACC4(acc0, xa)
      ACC4(acc1, xb)
      ACC4(acc2, xc)
      ACC4(acc3, xd)
    }
    int r = base + row_in_blk;
    if (r + 0 < n_rows) ((float4*)(Y + (size_t)(r + 0) * DDIM))[cg] = acc0;
    if (r + 1 < n_rows) ((float4*)(Y + (size_t)(r + 1) * DDIM))[cg] = acc1;
    if (r + 2 < n_rows) ((float4*)(Y + (size_t)(r + 2) * DDIM))[cg] = acc2;
    if (r + 3 < n_rows) ((float4*)(Y + (size_t)(r + 3) * DDIM))[cg] = acc3;
  }
}

// ---------------- segment mean (one wave per segment, 128 cols via float2) ----------------
__global__ __launch_bounds__(256) void seg_mean(
    const float* __restrict__ rows, const int* __restrict__ offs,
    const int* __restrict__ adj, float* __restrict__ out, int n_seg) {
  int w = (int)((blockIdx.x * 256 + threadIdx.x) >> 6);
  int lane = threadIdx.x & 63;
  if (w >= n_seg) return;
  int beg = offs[w], end = offs[w + 1];
  float2 acc = {0.f, 0.f};
  int j = beg;
  for (; j + 2 <= end; j += 2) {
    int s0 = adj[j], s1 = adj[j + 1];
    float2 v0 = ((const float2*)(rows + (size_t)s0 * DDIM))[lane];
    float2 v1 = ((const float2*)(rows + (size_t)s1 * DDIM))[lane];
    acc.x += v0.x + v1.x;
    acc.y += v0.y + v1.y;
  }
  if (j < end) {
    int s0 = adj[j];
    float2 v0 = ((const float2*)(rows + (size_t)s0 * DDIM))[lane];
    acc.x += v0.x;
    acc.y += v0.y;
  }
  float inv = (end > beg) ? 1.0f / (float)(end - beg) : 0.0f;
  float2 r;
  r.x = acc.x * inv;
  r.y = acc.y * inv;
  ((float2*)(out + (size_t)w * DDIM))[lane] = r;
}

template <int RELU>
__global__ __launch_bounds__(256) void seg_mean_bias(
    const float* __restrict__ rows, const int* __restrict__ offs,
    const int* __restrict__ adj, const float* __restrict__ bias,
    float* __restrict__ out, int n_seg) {
  int w = (int)((blockIdx.x * 256 + threadIdx.x) >> 6);
  int lane = threadIdx.x & 63;
  if (w >= n_seg) return;
  int beg = offs[w], end = offs[w + 1];
  float2 acc = {0.f, 0.f};
  int j = beg;
  for (; j + 2 <= end; j += 2) {
    int s0 = adj[j], s1 = adj[j + 1];
    float2 v0 = ((const float2*)(rows + (size_t)s0 * DDIM))[lane];
    float2 v1 = ((const float2*)(rows + (size_t)s1 * DDIM))[lane];
    acc.x += v0.x + v1.x;
    acc.y += v0.y + v1.y;
  }
  if (j < end) {
    int s0 = adj[j];
    float2 v0 = ((const float2*)(rows + (size_t)s0 * DDIM))[lane];
    acc.x += v0.x;
    acc.y += v0.y;
  }
  float inv = (end > beg) ? 1.0f / (float)(end - beg) : 0.0f;
  float2 b = ((const float2*)bias)[lane];
  float ox = acc.x * inv + b.x;
  float oy = acc.y * inv + b.y;
  if (RELU) {
    ox = fmaxf(ox, 0.f);
    oy = fmaxf(oy, 0.f);
  }
  float2 r;
  r.x = ox;
  r.y = oy;
  ((float2*)(out + (size_t)w * DDIM))[lane] = r;
}

extern "C" void kernel_launch(void* const* d_in, const int* in_sizes, int n_in,
                              void* d_out, int out_size, void* d_ws, size_t ws_size,
                              hipStream_t stream) {
  const float* x = (const float*)d_in[0];
  const int* eidx = (const int*)d_in[1];
  const float* W1 = (const float*)d_in[2];
  const float* b1 = (const float*)d_in[3];
  const float* W2 = (const float*)d_in[4];
  const float* b2 = (const float*)d_in[5];
  const int nnz = in_sizes[1] / 2;
  const int* src = eidx;
  const int* dst = eidx + nnz;
  float* outf = (float*)d_out;

  char* ws = (char*)d_ws;
  size_t off = 0;
  auto carve = [&](size_t bytes) -> char* {
    char* p = ws + off;
    off += (bytes + 255) & ~(size_t)255;
    return p;
  };
  float* he_raw = (float*)carve((size_t)N_HEDGES * DDIM * 4);  // A_e x (pre-GEMM)
  float* he = (float*)carve((size_t)N_HEDGES * DDIM * 4);      // (A_e x) @ W
  int* deg_e = (int*)carve((size_t)(N_HEDGES + N_NODES) * 4);  // contiguous for one memset
  int* deg_n = deg_e + N_HEDGES;
  int* offs_e = (int*)carve((size_t)(N_HEDGES + 1) * 4);
  int* offs_n = (int*)carve((size_t)(N_NODES + 1) * 4);
  int* cur_e = (int*)carve((size_t)N_HEDGES * 4);
  int* cur_n = (int*)carve((size_t)N_NODES * 4);
  int* adj_e = (int*)carve((size_t)nnz * 4);
  int* adj_n = (int*)carve((size_t)nnz * 4);
  int* aux = (int*)carve(64 * 4);

  hipMemsetAsync(deg_e, 0, (size_t)(N_HEDGES + N_NODES) * 4, stream);

  const int NB_E = (N_HEDGES + SCAN_BLK_ITEMS - 1) / SCAN_BLK_ITEMS;  // 3
  const int NB_N = (N_NODES + SCAN_BLK_ITEMS - 1) / SCAN_BLK_ITEMS;   // 13
  const int NB_TOT = NB_E + NB_N;                                     // 16

  hist_deg_grp<<<1024, 256, 0, stream>>>(src, dst, nnz, deg_e, deg_n);
  scan_pass1<<<NB_TOT, 256, 0, stream>>>(deg_e, deg_n, aux, NB_E);
  scan_pass2<<<1, 64, 0, stream>>>(aux, NB_E, NB_TOT, offs_e, offs_n, N_HEDGES, N_NODES);
  scan_pass3<<<NB_TOT, 256, 0, stream>>>(deg_e, deg_n, aux, NB_E, offs_e, offs_n, cur_e, cur_n);
  fill_csr_grp<<<1024, 256, 0, stream>>>(src, dst, nnz, cur_e, cur_n, adj_e, adj_n);

  // Linear-operator commutation: A_e (X W) == (A_e X) W, so aggregate first
  // and run the GEMM at the narrowest point (10000 rows instead of 50000).
  // ---- layer 1: h = relu(Dinv A_n ((Binv A_e x) W1) + b1) -> d_out ----
  seg_mean<<<(N_HEDGES + 3) / 4, 256, 0, stream>>>(x, offs_e, adj_e, he_raw, N_HEDGES);
  gemm128<<<(N_HEDGES + 31) / 32, 256, 0, stream>>>(he_raw, W1, he, N_HEDGES);
  seg_mean_bias<1><<<(N_NODES + 3) / 4, 256, 0, stream>>>(he, offs_n, adj_n, b1, outf, N_NODES);

  // ---- layer 2: out = Dinv A_n ((Binv A_e h) W2) + b2 ----
  seg_mean<<<(N_HEDGES + 3) / 4, 256, 0, stream>>>(outf, offs_e, adj_e, he_raw, N_HEDGES);
  gemm128<<<(N_HEDGES + 31) / 32, 256, 0, stream>>>(he_raw, W2, he, N_HEDGES);
  seg_mean_bias<0><<<(N_NODES + 3) / 4, 256, 0, stream>>>(he, offs_n, adj_n, b2, outf, N_NODES);
}